// Round 1
// baseline (1051.532 us; speedup 1.0000x reference)
//
#include <hip/hip_runtime.h>

typedef __bf16 bf16;
typedef bf16 bf16x4 __attribute__((ext_vector_type(4)));
typedef bf16 bf16x8 __attribute__((ext_vector_type(8)));
typedef float f32x4 __attribute__((ext_vector_type(4)));

static constexpr int BATCH = 16;
static constexpr int SEQ   = 2048;  // N
static constexpr int DH    = 512;   // H (== M)
static constexpr int ROWS  = BATCH * SEQ;  // 32768

__device__ __forceinline__ f32x4 mfma16(bf16x8 a, bf16x8 b, f32x4 c) {
    return __builtin_amdgcn_mfma_f32_16x16x32_bf16(a, b, c, 0, 0, 0);
}

// ---------------- fp32 -> bf16 (vectorized) ----------------
__global__ void cvt_bf16_kernel(const float* __restrict__ in, bf16* __restrict__ out, int n4) {
    int i = blockIdx.x * blockDim.x + threadIdx.x;
    const int stride = gridDim.x * blockDim.x;
    for (; i < n4; i += stride) {
        f32x4 f = *reinterpret_cast<const f32x4*>(in + (size_t)i * 4);
        bf16x4 o;
        o[0] = (bf16)f[0]; o[1] = (bf16)f[1]; o[2] = (bf16)f[2]; o[3] = (bf16)f[3];
        *reinterpret_cast<bf16x4*>(out + (size_t)i * 4) = o;
    }
}

// ---------------- weight [K=512][N=512] fp32 -> [N][K] bf16 ----------------
__global__ void cvt_wT_kernel(const float* __restrict__ in, bf16* __restrict__ out) {
    int idx = blockIdx.x * 256 + threadIdx.x;  // idx = n*512 + k
    int n = idx >> 9, k = idx & 511;
    out[idx] = (bf16)in[k * 512 + n];
}

// ---------------- generic GEMM: Y = relu(X[R,512] @ W[512,512] + b) ----------------
// Wt is [n][k] (pre-transposed) so B-fragments are contiguous 16B loads.
// OMODE 0: bf16 row-major out. 1: bf16 row-major + transposed copy [B][512][2048]. 2: fp32 out.
template <int OMODE>
__global__ __launch_bounds__(256, 2)
void gemm_relu_kernel(const bf16* __restrict__ X, const bf16* __restrict__ Wt,
                      const float* __restrict__ bias,
                      bf16* __restrict__ Y, bf16* __restrict__ Yt,
                      float* __restrict__ Yf)
{
    const int lane = threadIdx.x & 63, wid = threadIdx.x >> 6;
    const int wr = wid >> 1, wc = wid & 1;
    const int r0 = blockIdx.x * 128 + wr * 64;
    const int c0 = blockIdx.y * 128 + wc * 64;
    const int lrow = lane & 15, lhi = lane >> 4;

    f32x4 acc[4][4] = {};
    for (int kc = 0; kc < 512; kc += 32) {
        const int ko = kc + lhi * 8;
        bf16x8 af[4], bfr[4];
        #pragma unroll
        for (int t = 0; t < 4; ++t)
            af[t] = *reinterpret_cast<const bf16x8*>(X + (size_t)(r0 + t * 16 + lrow) * 512 + ko);
        #pragma unroll
        for (int t = 0; t < 4; ++t)
            bfr[t] = *reinterpret_cast<const bf16x8*>(Wt + (size_t)(c0 + t * 16 + lrow) * 512 + ko);
        #pragma unroll
        for (int i = 0; i < 4; ++i)
            #pragma unroll
            for (int j = 0; j < 4; ++j)
                acc[i][j] = mfma16(af[i], bfr[j], acc[i][j]);
    }

    #pragma unroll
    for (int i = 0; i < 4; ++i) {
        #pragma unroll
        for (int j = 0; j < 4; ++j) {
            const int col = c0 + j * 16 + lrow;
            const float bb = bias[col];
            #pragma unroll
            for (int rg = 0; rg < 4; ++rg) {
                const int r = r0 + i * 16 + lhi * 4 + rg;
                float y = acc[i][j][rg] + bb;
                y = y > 0.f ? y : 0.f;
                if (OMODE == 2) {
                    Yf[(size_t)r * 512 + col] = y;
                } else {
                    Y[(size_t)r * 512 + col] = (bf16)y;
                    if (OMODE == 1) {
                        const int bi = r >> 11, nn = r & 2047;
                        Yt[((size_t)bi * 512 + col) * 2048 + nn] = (bf16)y;
                    }
                }
            }
        }
    }
}

// ---------------- fused attention ----------------
// scores = (Q K^T) * (-A); att = softmax_m(scores); O = att @ V + V  (bf16 out)
// Block: 64 q-rows, 8 waves. S phase: wave (wr,wc) computes 16x32 of S.
// PV phase: wave w owns h-slice [64w, 64w+64) for all 64 rows.
__global__ __launch_bounds__(512, 2)
void attn_kernel(const bf16* __restrict__ Q, const bf16* __restrict__ K,
                 const bf16* __restrict__ Vt, const bf16* __restrict__ V,
                 const float* __restrict__ A, bf16* __restrict__ O)
{
    __shared__ float S_lds[64][68];
    __shared__ bf16 P_lds[64 * 64];   // row stride 128B, 16B blocks XOR-swizzled by (row&7)
    __shared__ float m_lds[64], l_lds[64], sc_lds[64];

    const int tid = threadIdx.x;
    const int lane = tid & 63, wid = tid >> 6;
    const int wr = wid >> 1, wc = wid & 1;
    const int lrow = lane & 15, lhi = lane >> 4;
    const int bb = blockIdx.y;
    const int n0 = blockIdx.x * 64;
    const int h0 = wid * 64;

    if (tid < 64) { m_lds[tid] = -1e30f; l_lds[tid] = 0.f; }
    __syncthreads();

    // Q fragments for this wave's S rows (kept resident: 16 x 16B = 64 VGPRs)
    bf16x8 qf[16];
    {
        const bf16* qp = Q + (size_t)(bb * SEQ + n0 + wr * 16 + lrow) * DH + lhi * 8;
        #pragma unroll
        for (int kk = 0; kk < 16; ++kk)
            qf[kk] = *reinterpret_cast<const bf16x8*>(qp + kk * 32);
    }

    f32x4 acc[4][4] = {};  // [row-tile][h-tile] for PV

    for (int m0 = 0; m0 < SEQ; m0 += 64) {
        // ---- phase 1: S = (Q K^T) * (-A) -> S_lds ----
        f32x4 s0 = {}, s1 = {};
        {
            const bf16* kp = K + (size_t)(bb * SEQ + m0 + wc * 32 + lrow) * DH + lhi * 8;
            #pragma unroll
            for (int kk = 0; kk < 16; ++kk) {
                bf16x8 k0 = *reinterpret_cast<const bf16x8*>(kp + kk * 32);
                bf16x8 k1 = *reinterpret_cast<const bf16x8*>(kp + (size_t)16 * DH + kk * 32);
                s0 = mfma16(qf[kk], k0, s0);
                s1 = mfma16(qf[kk], k1, s1);
            }
        }
        {
            const int srow = wr * 16 + lhi * 4;
            const float* ap = A + ((size_t)bb * SEQ + n0 + srow) * SEQ + m0 + wc * 32 + lrow;
            #pragma unroll
            for (int rg = 0; rg < 4; ++rg) {
                S_lds[srow + rg][wc * 32 + lrow]      = s0[rg] * (-ap[(size_t)rg * SEQ]);
                S_lds[srow + rg][wc * 32 + 16 + lrow] = s1[rg] * (-ap[(size_t)rg * SEQ + 16]);
            }
        }
        __syncthreads();

        // ---- phase 2: online softmax stats + P (bf16) ----
        {
            const int row = tid >> 3, c8 = (tid & 7) * 8;
            float sv[8];
            #pragma unroll
            for (int j = 0; j < 8; ++j) sv[j] = S_lds[row][c8 + j];
            float mx = sv[0];
            #pragma unroll
            for (int j = 1; j < 8; ++j) mx = fmaxf(mx, sv[j]);
            mx = fmaxf(mx, __shfl_xor(mx, 1));
            mx = fmaxf(mx, __shfl_xor(mx, 2));
            mx = fmaxf(mx, __shfl_xor(mx, 4));
            const float m_old = m_lds[row];
            const float m_new = fmaxf(m_old, mx);
            float sum = 0.f;
            bf16x8 pw;
            #pragma unroll
            for (int j = 0; j < 8; ++j) {
                float p = __expf(sv[j] - m_new);
                sum += p;
                pw[j] = (bf16)p;
            }
            sum += __shfl_xor(sum, 1);
            sum += __shfl_xor(sum, 2);
            sum += __shfl_xor(sum, 4);
            const float scale = __expf(m_old - m_new);
            if ((tid & 7) == 0) {
                m_lds[row] = m_new;
                l_lds[row] = l_lds[row] * scale + sum;
                sc_lds[row] = scale;
            }
            const int blk = (tid & 7) ^ (row & 7);
            *reinterpret_cast<bf16x8*>(&P_lds[row * 64 + blk * 8]) = pw;
        }
        __syncthreads();

        // ---- phase 3: rescale acc, PV ----
        #pragma unroll
        for (int rt = 0; rt < 4; ++rt) {
            #pragma unroll
            for (int rg = 0; rg < 4; ++rg) {
                const float sc = sc_lds[rt * 16 + lhi * 4 + rg];
                #pragma unroll
                for (int ht = 0; ht < 4; ++ht) acc[rt][ht][rg] *= sc;
            }
        }
        bf16x8 pf[4][2];
        #pragma unroll
        for (int rt = 0; rt < 4; ++rt) {
            #pragma unroll
            for (int kc = 0; kc < 2; ++kc) {
                const int prow = rt * 16 + lrow;
                const int blk = (kc * 4 + lhi) ^ (prow & 7);
                pf[rt][kc] = *reinterpret_cast<const bf16x8*>(&P_lds[prow * 64 + blk * 8]);
            }
        }
        const bf16* vp = Vt + ((size_t)bb * DH + h0 + lrow) * SEQ + m0 + lhi * 8;
        #pragma unroll
        for (int ht = 0; ht < 4; ++ht) {
            #pragma unroll
            for (int kc = 0; kc < 2; ++kc) {
                bf16x8 vf = *reinterpret_cast<const bf16x8*>(vp + (size_t)ht * 16 * SEQ + kc * 32);
                #pragma unroll
                for (int rt = 0; rt < 4; ++rt)
                    acc[rt][ht] = mfma16(pf[rt][kc], vf, acc[rt][ht]);
            }
        }
        __syncthreads();
    }

    // ---- epilogue: /l, + V, store bf16 ----
    #pragma unroll
    for (int rt = 0; rt < 4; ++rt) {
        #pragma unroll
        for (int rg = 0; rg < 4; ++rg) {
            const int row = rt * 16 + lhi * 4 + rg;
            const float inv = 1.f / l_lds[row];
            const size_t rbase = (size_t)(bb * SEQ + n0 + row) * DH;
            #pragma unroll
            for (int ht = 0; ht < 4; ++ht) {
                const int col = h0 + ht * 16 + lrow;
                const float vv = (float)V[rbase + col];
                O[rbase + col] = (bf16)(acc[rt][ht][rg] * inv + vv);
            }
        }
    }
}

extern "C" void kernel_launch(void* const* d_in, const int* in_sizes, int n_in,
                              void* d_out, int out_size, void* d_ws, size_t ws_size,
                              hipStream_t stream) {
    const float* A    = (const float*)d_in[0];
    const float* h    = (const float*)d_in[1];
    const float* Wv1  = (const float*)d_in[2];
    const float* bv1  = (const float*)d_in[3];
    const float* Wv2  = (const float*)d_in[4];
    const float* bv2  = (const float*)d_in[5];
    const float* Wk   = (const float*)d_in[6];   // NOTE: Wk before Wq in dict order
    const float* bk   = (const float*)d_in[7];
    const float* Wq   = (const float*)d_in[8];
    const float* bq   = (const float*)d_in[9];
    const float* Wout = (const float*)d_in[10];
    const float* bout = (const float*)d_in[11];
    float* out = (float*)d_out;

    char* ws = (char*)d_ws;
    const size_t SZ = (size_t)ROWS * 512 * sizeof(bf16);  // 33.5 MB
    bf16* hb   = (bf16*)(ws + 0 * SZ);  // h in bf16; later reused as attention output
    bf16* tq   = (bf16*)(ws + 1 * SZ);  // t = relu(h@Wv1), later overwritten with q
    bf16* kb   = (bf16*)(ws + 2 * SZ);
    bf16* vb   = (bf16*)(ws + 3 * SZ);
    bf16* vtb  = (bf16*)(ws + 4 * SZ);  // v transposed: [B][H][N]
    bf16* wbase = (bf16*)(ws + 5 * SZ); // 5 x 512KB bf16 weights
    bf16* Wv1t  = wbase + 0 * 262144;
    bf16* Wv2t  = wbase + 1 * 262144;
    bf16* Wqt   = wbase + 2 * 262144;
    bf16* Wkt   = wbase + 3 * 262144;
    bf16* Woutt = wbase + 4 * 262144;
    bf16* ob = hb;  // attention output aliases hb (hb dead after k projection)

    cvt_bf16_kernel<<<4096, 256, 0, stream>>>(h, hb, ROWS * 512 / 4);
    cvt_wT_kernel<<<1024, 256, 0, stream>>>(Wv1, Wv1t);
    cvt_wT_kernel<<<1024, 256, 0, stream>>>(Wv2, Wv2t);
    cvt_wT_kernel<<<1024, 256, 0, stream>>>(Wq, Wqt);
    cvt_wT_kernel<<<1024, 256, 0, stream>>>(Wk, Wkt);
    cvt_wT_kernel<<<1024, 256, 0, stream>>>(Wout, Woutt);

    dim3 gg(ROWS / 128, 512 / 128);  // (256, 4)
    gemm_relu_kernel<0><<<gg, 256, 0, stream>>>(hb, Wv1t, bv1, tq, nullptr, nullptr);  // t
    gemm_relu_kernel<1><<<gg, 256, 0, stream>>>(tq, Wv2t, bv2, vb, vtb, nullptr);      // v + vT
    gemm_relu_kernel<0><<<gg, 256, 0, stream>>>(hb, Wqt, bq, tq, nullptr, nullptr);    // q (over t)
    gemm_relu_kernel<0><<<gg, 256, 0, stream>>>(hb, Wkt, bk, kb, nullptr, nullptr);    // k

    dim3 ga(SEQ / 64, BATCH);  // (32, 16)
    attn_kernel<<<ga, 512, 0, stream>>>(tq, kb, vtb, vb, A, ob);

    gemm_relu_kernel<2><<<gg, 256, 0, stream>>>(ob, Woutt, bout, nullptr, nullptr, out);
}

// Round 2
// 634.923 us; speedup vs baseline: 1.6562x; 1.6562x over previous
//
#include <hip/hip_runtime.h>

typedef __bf16 bf16;
typedef bf16 bf16x4 __attribute__((ext_vector_type(4)));
typedef bf16 bf16x8 __attribute__((ext_vector_type(8)));
typedef float f32x4 __attribute__((ext_vector_type(4)));

static constexpr int BATCH = 16;
static constexpr int SEQ   = 2048;  // N
static constexpr int DH    = 512;   // H (== M)
static constexpr int ROWS  = BATCH * SEQ;  // 32768

__device__ __forceinline__ f32x4 mfma16(bf16x8 a, bf16x8 b, f32x4 c) {
    return __builtin_amdgcn_mfma_f32_16x16x32_bf16(a, b, c, 0, 0, 0);
}

// async global->LDS, 16B per lane. dst must be wave-uniform base (HW adds lane*16).
__device__ __forceinline__ void gl_lds16(const bf16* g, bf16* l) {
    __builtin_amdgcn_global_load_lds((const __attribute__((address_space(1))) void*)g,
                                     (__attribute__((address_space(3))) void*)l, 16, 0, 0);
}

// ---------------- fp32 -> bf16 (vectorized) ----------------
__global__ void cvt_bf16_kernel(const float* __restrict__ in, bf16* __restrict__ out, int n4) {
    int i = blockIdx.x * blockDim.x + threadIdx.x;
    const int stride = gridDim.x * blockDim.x;
    for (; i < n4; i += stride) {
        f32x4 f = *reinterpret_cast<const f32x4*>(in + (size_t)i * 4);
        bf16x4 o;
        o[0] = (bf16)f[0]; o[1] = (bf16)f[1]; o[2] = (bf16)f[2]; o[3] = (bf16)f[3];
        *reinterpret_cast<bf16x4*>(out + (size_t)i * 4) = o;
    }
}

// ---------------- weight [K=512][N=512] fp32 -> [N][K] bf16 ----------------
__global__ void cvt_wT_kernel(const float* __restrict__ in, bf16* __restrict__ out) {
    int idx = blockIdx.x * 256 + threadIdx.x;  // idx = n*512 + k
    int n = idx >> 9, k = idx & 511;
    out[idx] = (bf16)in[k * 512 + n];
}

// ---------------- GEMM: Y = relu(X[R,512] @ W[512,512] + b), m97-style LDS staging ----
// Wt is [n][k]. 128x128 tile, BK=64, double-buffered LDS via global_load_lds,
// XOR-swizzled (block^(row&7)) so ds_read_b128 is conflict-free.
// OMODE 0: bf16 out. 1: bf16 out + transposed copy [B][512][2048]. 2: fp32 out.
template <int OMODE>
__global__ __launch_bounds__(256, 2)
void gemm_relu_kernel(const bf16* __restrict__ X, const bf16* __restrict__ Wt,
                      const float* __restrict__ bias,
                      bf16* __restrict__ Y, bf16* __restrict__ Yt,
                      float* __restrict__ Yf)
{
    __shared__ bf16 Xl[2][128 * 64];
    __shared__ bf16 Wl[2][128 * 64];

    const int tid = threadIdx.x;
    const int lane = tid & 63, wid = tid >> 6;
    const int wr = wid >> 1, wc = wid & 1;
    const int r0 = blockIdx.x * 128;
    const int c0 = blockIdx.y * 128;
    const int lrow = lane & 15, lhi = lane >> 4;

    // staging geometry: per call 256 thr x 16B = 4KB = 32 rows of 128B
    const int srow = tid >> 3;            // 0..31 within call
    const int skb  = (tid & 7) ^ (srow & 7);  // pre-swizzled source block
    const int sdst = wid * 512;           // element offset of this wave's 1KB chunk

    auto stage = [&](int buf, int kc) {
        const bf16* xs = X + (size_t)r0 * 512 + kc * 64;
        const bf16* ws = Wt + (size_t)c0 * 512 + kc * 64;
        #pragma unroll
        for (int c = 0; c < 4; ++c) {
            const int row = c * 32 + srow;
            gl_lds16(xs + (size_t)row * 512 + skb * 8, &Xl[buf][c * 2048 + sdst]);
        }
        #pragma unroll
        for (int c = 0; c < 4; ++c) {
            const int row = c * 32 + srow;
            gl_lds16(ws + (size_t)row * 512 + skb * 8, &Wl[buf][c * 2048 + sdst]);
        }
    };

    f32x4 acc[4][4] = {};

    stage(0, 0);
    __syncthreads();

    for (int t = 0; t < 8; ++t) {
        const int buf = t & 1;
        if (t + 1 < 8) stage(buf ^ 1, t + 1);
        #pragma unroll
        for (int kk = 0; kk < 2; ++kk) {
            bf16x8 af[4], bfr[4];
            const int kb = kk * 4 + lhi;
            #pragma unroll
            for (int tt = 0; tt < 4; ++tt) {
                const int ra = wr * 64 + tt * 16 + lrow;
                af[tt] = *reinterpret_cast<const bf16x8*>(&Xl[buf][ra * 64 + ((kb ^ (ra & 7)) * 8)]);
            }
            #pragma unroll
            for (int tt = 0; tt < 4; ++tt) {
                const int rb = wc * 64 + tt * 16 + lrow;
                bfr[tt] = *reinterpret_cast<const bf16x8*>(&Wl[buf][rb * 64 + ((kb ^ (rb & 7)) * 8)]);
            }
            #pragma unroll
            for (int i = 0; i < 4; ++i)
                #pragma unroll
                for (int j = 0; j < 4; ++j)
                    acc[i][j] = mfma16(af[i], bfr[j], acc[i][j]);
        }
        __syncthreads();
    }

    #pragma unroll
    for (int i = 0; i < 4; ++i) {
        #pragma unroll
        for (int j = 0; j < 4; ++j) {
            const int col = c0 + wc * 64 + j * 16 + lrow;
            const float bb = bias[col];
            #pragma unroll
            for (int rg = 0; rg < 4; ++rg) {
                const int r = r0 + wr * 64 + i * 16 + lhi * 4 + rg;
                float y = acc[i][j][rg] + bb;
                y = y > 0.f ? y : 0.f;
                if (OMODE == 2) {
                    Yf[(size_t)r * 512 + col] = y;
                } else {
                    Y[(size_t)r * 512 + col] = (bf16)y;
                    if (OMODE == 1) {
                        const int bi = r >> 11, nn = r & 2047;
                        Yt[((size_t)bi * 512 + col) * 2048 + nn] = (bf16)y;
                    }
                }
            }
        }
    }
}

// ---------------- fused attention ----------------
// scores = (Q K^T) * (-A); att = softmax(scores); O = att @ V + V  (bf16 out)
// Block: 64 q-rows, 8 waves. K tile + Vt tile staged via global_load_lds
// (pre-swizzled source -> XOR(blk, row&7) layout, conflict-free ds_read_b128).
// Softmax in-register on MFMA output layout; cross-wc combine via tiny LDS.
__global__ __launch_bounds__(512, 2)
void attn_kernel(const bf16* __restrict__ Q, const bf16* __restrict__ K,
                 const bf16* __restrict__ Vt, const bf16* __restrict__ V,
                 const float* __restrict__ A, bf16* __restrict__ O)
{
    __shared__ bf16 K_lds[64 * 512];    // [kv-row][depth] swizzled, 64KB
    __shared__ bf16 Vt_lds[512 * 64];   // [h][kv] swizzled, 64KB
    __shared__ bf16 P_lds[64 * 64];     // swizzled, 8KB
    __shared__ float m_lds[64], l_lds[64], sc_lds[64];
    __shared__ float mxp_lds[2][64], sump_lds[2][64];

    const int tid = threadIdx.x;
    const int lane = tid & 63, wid = tid >> 6;
    const int wr = wid >> 1, wc = wid & 1;
    const int lrow = lane & 15, lhi = lane >> 4;

    // XCD-aware mapping: batch b's 32 q-tiles land on one XCD (K/V L2 reuse)
    const int id = blockIdx.x;
    const int slot = id >> 3;
    const int bb = (id & 7) + 8 * (slot >> 5);
    const int n0 = (slot & 31) * 64;
    const int srow_base = wr * 16 + lhi * 4;

    if (tid < 64) { m_lds[tid] = -1e30f; l_lds[tid] = 0.f; }

    const bf16* Kbase  = K + (size_t)bb * SEQ * DH;
    const bf16* Vtbase = Vt + (size_t)bb * DH * SEQ;

    // stage K[0]
    #pragma unroll
    for (int c = 0; c < 8; ++c) {
        const int row = wid * 8 + c;
        gl_lds16(Kbase + (size_t)row * DH + ((lane ^ (row & 7)) * 8), &K_lds[row * 512]);
    }

    // Q fragments resident (16 x 16B)
    bf16x8 qf[16];
    {
        const bf16* qp = Q + (size_t)(bb * SEQ + n0 + wr * 16 + lrow) * DH + lhi * 8;
        #pragma unroll
        for (int kk = 0; kk < 16; ++kk)
            qf[kk] = *reinterpret_cast<const bf16x8*>(qp + kk * 32);
    }

    __syncthreads();

    f32x4 acc[4][4] = {};  // [row-tile][h-tile]

    for (int it = 0; it < 32; ++it) {
        const int m0 = it * 64;

        // A loads (consumed after QK^T; hidden under phase 1)
        float av0[4], av1[4];
        {
            const float* ap = A + ((size_t)bb * SEQ + n0 + srow_base) * SEQ + m0 + wc * 32 + lrow;
            #pragma unroll
            for (int rg = 0; rg < 4; ++rg) {
                av0[rg] = ap[(size_t)rg * SEQ];
                av1[rg] = ap[(size_t)rg * SEQ + 16];
            }
        }
        // stage Vt[it] (consumed in PV after B2; overlaps phase 1 + softmax)
        #pragma unroll
        for (int c = 0; c < 8; ++c) {
            const int rowg = (wid * 8 + c) * 8;
            const int row = rowg + (lane >> 3);
            gl_lds16(Vtbase + (size_t)row * SEQ + m0 + (((lane & 7) ^ (lane >> 3)) * 8),
                     &Vt_lds[rowg * 64]);
        }

        // ---- phase 1: S = Q K^T from LDS ----
        f32x4 s0 = {}, s1 = {};
        {
            const int kr0 = wc * 32 + lrow, kr1 = kr0 + 16;
            #pragma unroll
            for (int kk = 0; kk < 16; ++kk) {
                const int kb = kk * 4 + lhi;
                bf16x8 k0 = *reinterpret_cast<const bf16x8*>(&K_lds[kr0 * 512 + ((kb ^ (kr0 & 7)) * 8)]);
                bf16x8 k1 = *reinterpret_cast<const bf16x8*>(&K_lds[kr1 * 512 + ((kb ^ (kr1 & 7)) * 8)]);
                s0 = mfma16(qf[kk], k0, s0);
                s1 = mfma16(qf[kk], k1, s1);
            }
        }
        // scores * (-A), per-row max (16 lanes share a row)
        float x0[4], x1[4];
        #pragma unroll
        for (int rg = 0; rg < 4; ++rg) {
            x0[rg] = s0[rg] * (-av0[rg]);
            x1[rg] = s1[rg] * (-av1[rg]);
            float m = fmaxf(x0[rg], x1[rg]);
            m = fmaxf(m, __shfl_xor(m, 1));
            m = fmaxf(m, __shfl_xor(m, 2));
            m = fmaxf(m, __shfl_xor(m, 4));
            m = fmaxf(m, __shfl_xor(m, 8));
            if (lrow == 0) mxp_lds[wc][srow_base + rg] = m;
        }
        __syncthreads();  // B1

        // stage K[it+1] (drains at B2; partial overlap with softmax)
        if (it + 1 < 32) {
            #pragma unroll
            for (int c = 0; c < 8; ++c) {
                const int row = wid * 8 + c;
                gl_lds16(Kbase + (size_t)(m0 + 64 + row) * DH + ((lane ^ (row & 7)) * 8),
                         &K_lds[row * 512]);
            }
        }

        // ---- phase 2: softmax in-register ----
        #pragma unroll
        for (int rg = 0; rg < 4; ++rg) {
            const int row = srow_base + rg;
            const float mt = fmaxf(mxp_lds[0][row], mxp_lds[1][row]);
            const float mo = m_lds[row];
            const float mn = fmaxf(mo, mt);
            const float p0 = __expf(x0[rg] - mn);
            const float p1 = __expf(x1[rg] - mn);
            const int c0i = wc * 32 + lrow, c1i = c0i + 16;
            P_lds[row * 64 + (((c0i >> 3) ^ (row & 7)) * 8) + (c0i & 7)] = (bf16)p0;
            P_lds[row * 64 + (((c1i >> 3) ^ (row & 7)) * 8) + (c1i & 7)] = (bf16)p1;
            float s = p0 + p1;
            s += __shfl_xor(s, 1);
            s += __shfl_xor(s, 2);
            s += __shfl_xor(s, 4);
            s += __shfl_xor(s, 8);
            if (lrow == 0) {
                sump_lds[wc][row] = s;
                if (wc == 0) { sc_lds[row] = __expf(mo - mn); m_lds[row] = mn; }
            }
        }
        __syncthreads();  // B2

        // l update (readers only at epilogue)
        if (tid < 64) l_lds[tid] = l_lds[tid] * sc_lds[tid] + sump_lds[0][tid] + sump_lds[1][tid];

        // ---- phase 3: rescale + PV ----
        #pragma unroll
        for (int rt = 0; rt < 4; ++rt) {
            #pragma unroll
            for (int rg = 0; rg < 4; ++rg) {
                const float sc = sc_lds[rt * 16 + lhi * 4 + rg];
                #pragma unroll
                for (int ht = 0; ht < 4; ++ht) acc[rt][ht][rg] *= sc;
            }
        }
        bf16x8 pf[4][2];
        #pragma unroll
        for (int rt = 0; rt < 4; ++rt) {
            const int prow = rt * 16 + lrow;
            #pragma unroll
            for (int kc = 0; kc < 2; ++kc)
                pf[rt][kc] = *reinterpret_cast<const bf16x8*>(
                    &P_lds[prow * 64 + (((kc * 4 + lhi) ^ (prow & 7)) * 8)]);
        }
        const int h0 = wid * 64;
        #pragma unroll
        for (int ht = 0; ht < 4; ++ht) {
            const int vrow = h0 + ht * 16 + lrow;
            #pragma unroll
            for (int kc = 0; kc < 2; ++kc) {
                bf16x8 vf = *reinterpret_cast<const bf16x8*>(
                    &Vt_lds[vrow * 64 + (((kc * 4 + lhi) ^ (vrow & 7)) * 8)]);
                #pragma unroll
                for (int rt = 0; rt < 4; ++rt)
                    acc[rt][ht] = mfma16(pf[rt][kc], vf, acc[rt][ht]);
            }
        }
        __syncthreads();  // B3
    }

    // ---- epilogue: /l, + V, store bf16 ----
    const int h0 = wid * 64;
    #pragma unroll
    for (int rt = 0; rt < 4; ++rt) {
        #pragma unroll
        for (int rg = 0; rg < 4; ++rg) {
            const int row = rt * 16 + lhi * 4 + rg;
            const float inv = 1.f / l_lds[row];
            const size_t rbase = (size_t)(bb * SEQ + n0 + row) * DH;
            #pragma unroll
            for (int ht = 0; ht < 4; ++ht) {
                const int col = h0 + ht * 16 + lrow;
                const float vv = (float)V[rbase + col];
                O[rbase + col] = (bf16)(acc[rt][ht][rg] * inv + vv);
            }
        }
    }
}

extern "C" void kernel_launch(void* const* d_in, const int* in_sizes, int n_in,
                              void* d_out, int out_size, void* d_ws, size_t ws_size,
                              hipStream_t stream) {
    const float* A    = (const float*)d_in[0];
    const float* h    = (const float*)d_in[1];
    const float* Wv1  = (const float*)d_in[2];
    const float* bv1  = (const float*)d_in[3];
    const float* Wv2  = (const float*)d_in[4];
    const float* bv2  = (const float*)d_in[5];
    const float* Wk   = (const float*)d_in[6];   // NOTE: Wk before Wq in dict order
    const float* bk   = (const float*)d_in[7];
    const float* Wq   = (const float*)d_in[8];
    const float* bq   = (const float*)d_in[9];
    const float* Wout = (const float*)d_in[10];
    const float* bout = (const float*)d_in[11];
    float* out = (float*)d_out;

    char* ws = (char*)d_ws;
    const size_t SZ = (size_t)ROWS * 512 * sizeof(bf16);  // 33.5 MB
    bf16* hb   = (bf16*)(ws + 0 * SZ);  // h in bf16; later reused as attention output
    bf16* tq   = (bf16*)(ws + 1 * SZ);  // t = relu(h@Wv1), later overwritten with q
    bf16* kb   = (bf16*)(ws + 2 * SZ);
    bf16* vb   = (bf16*)(ws + 3 * SZ);
    bf16* vtb  = (bf16*)(ws + 4 * SZ);  // v transposed: [B][H][N]
    bf16* wbase = (bf16*)(ws + 5 * SZ); // 5 x 512KB bf16 weights
    bf16* Wv1t  = wbase + 0 * 262144;
    bf16* Wv2t  = wbase + 1 * 262144;
    bf16* Wqt   = wbase + 2 * 262144;
    bf16* Wkt   = wbase + 3 * 262144;
    bf16* Woutt = wbase + 4 * 262144;
    bf16* ob = hb;  // attention output aliases hb (hb dead after k projection)

    cvt_bf16_kernel<<<4096, 256, 0, stream>>>(h, hb, ROWS * 512 / 4);
    cvt_wT_kernel<<<1024, 256, 0, stream>>>(Wv1, Wv1t);
    cvt_wT_kernel<<<1024, 256, 0, stream>>>(Wv2, Wv2t);
    cvt_wT_kernel<<<1024, 256, 0, stream>>>(Wq, Wqt);
    cvt_wT_kernel<<<1024, 256, 0, stream>>>(Wk, Wkt);
    cvt_wT_kernel<<<1024, 256, 0, stream>>>(Wout, Woutt);

    dim3 gg(ROWS / 128, 512 / 128);  // (256, 4)
    gemm_relu_kernel<0><<<gg, 256, 0, stream>>>(hb, Wv1t, bv1, tq, nullptr, nullptr);  // t
    gemm_relu_kernel<1><<<gg, 256, 0, stream>>>(tq, Wv2t, bv2, vb, vtb, nullptr);      // v + vT
    gemm_relu_kernel<0><<<gg, 256, 0, stream>>>(hb, Wqt, bq, tq, nullptr, nullptr);    // q (over t)
    gemm_relu_kernel<0><<<gg, 256, 0, stream>>>(hb, Wkt, bk, kb, nullptr, nullptr);    // k

    attn_kernel<<<dim3(512), 512, 0, stream>>>(tq, kb, vtb, vb, A, ob);

    gemm_relu_kernel<2><<<gg, 256, 0, stream>>>(ob, Woutt, bout, nullptr, nullptr, out);
}